// Round 1
// baseline (701.993 us; speedup 1.0000x reference)
//
#include <hip/hip_runtime.h>
#include <hip/hip_bf16.h>

#define N_NODES 50000
#define NFEAT 5
#define HIDDEN 256
#define NCLASS 5
#define N_EDGES 800000

// ---------------------------------------------------------------------------
// Edge-index dtype detection: if input is int64 (little-endian), every odd
// 32-bit word (high word of a small nonneg int64) is 0. With int32 data these
// words are random node ids -> OR != 0.
__global__ void detect_kernel(const int* __restrict__ raw, int* __restrict__ flag) {
    __shared__ int any;
    if (threadIdx.x == 0) any = 0;
    __syncthreads();
    int v = 0;
    for (int i = threadIdx.x; i < N_EDGES; i += 1024) v |= raw[2 * i + 1];
    if (v) atomicOr(&any, 1);
    __syncthreads();
    if (threadIdx.x == 0) *flag = (any == 0) ? 1 : 0;
}

// Normalize edge_index to int32 in workspace (handles int64 or int32 input).
__global__ void normalize_kernel(const int* __restrict__ raw, const int* __restrict__ flag,
                                 int* __restrict__ ei) {
    int i = blockIdx.x * 256 + threadIdx.x;
    if (i >= 2 * N_EDGES) return;
    ei[i] = (*flag) ? raw[2 * i] : raw[i];
}

// ---------------------------------------------------------------------------
// CSR build
__global__ void count_kernel(const int* __restrict__ ei, int* __restrict__ cnt) {
    int e = blockIdx.x * 256 + threadIdx.x;
    if (e < N_EDGES) atomicAdd(&cnt[ei[N_EDGES + e]], 1);
}

__global__ void scan_kernel(const int* __restrict__ cnt, int* __restrict__ off,
                            int* __restrict__ cursor, float* __restrict__ invdeg) {
    __shared__ int s[1024];
    __shared__ int carry_s;
    int tid = threadIdx.x;
    if (tid == 0) carry_s = 0;
    __syncthreads();
    for (int base = 0; base < N_NODES; base += 1024) {
        int i = base + tid;
        int v = (i < N_NODES) ? cnt[i] : 0;
        s[tid] = v;
        __syncthreads();
        for (int ofs = 1; ofs < 1024; ofs <<= 1) {
            int t = (tid >= ofs) ? s[tid - ofs] : 0;
            __syncthreads();
            s[tid] += t;
            __syncthreads();
        }
        int excl = s[tid] - v;
        int c = carry_s;
        if (i < N_NODES) {
            off[i] = c + excl;
            cursor[i] = c + excl;
            invdeg[i] = 1.0f / fmaxf((float)v, 1.0f);
        }
        __syncthreads();
        if (tid == 1023) carry_s += s[1023];
        __syncthreads();
    }
    if (tid == 0) off[N_NODES] = carry_s;
}

__global__ void scatter_kernel(const int* __restrict__ ei, int* __restrict__ cursor,
                               int* __restrict__ csr) {
    int e = blockIdx.x * 256 + threadIdx.x;
    if (e < N_EDGES) {
        int src = ei[e], dst = ei[N_EDGES + e];
        int pos = atomicAdd(&cursor[dst], 1);
        csr[pos] = src;
    }
}

// ---------------------------------------------------------------------------
// Layer 1: mean-aggregate x (5 features) per node
__global__ void agg1_kernel(const float* __restrict__ x, const int* __restrict__ off,
                            const int* __restrict__ csr, const float* __restrict__ invdeg,
                            float* __restrict__ agg1) {
    int n = blockIdx.x * 256 + threadIdx.x;
    if (n >= N_NODES) return;
    float a[NFEAT] = {0.f, 0.f, 0.f, 0.f, 0.f};
    int e0 = off[n], e1 = off[n + 1];
    for (int e = e0; e < e1; ++e) {
        int s = csr[e];
#pragma unroll
        for (int k = 0; k < NFEAT; ++k) a[k] += x[s * NFEAT + k];
    }
    float inv = invdeg[n];
#pragma unroll
    for (int k = 0; k < NFEAT; ++k) agg1[n * NFEAT + k] = a[k] * inv;
}

// Layer 1 dense: h1 = relu(agg1 @ W1_l + b1 + x @ W1_r); one block per node
__global__ void dense1_kernel(const float* __restrict__ x, const float* __restrict__ agg1,
                              const float* __restrict__ W1l, const float* __restrict__ b1,
                              const float* __restrict__ W1r, float* __restrict__ h1) {
    int n = blockIdx.x;
    __shared__ float xa[NFEAT], ag[NFEAT];
    int f = threadIdx.x;
    if (f < NFEAT) {
        xa[f] = x[n * NFEAT + f];
        ag[f] = agg1[n * NFEAT + f];
    }
    __syncthreads();
    float acc = b1[f];
#pragma unroll
    for (int k = 0; k < NFEAT; ++k)
        acc += ag[k] * W1l[k * HIDDEN + f] + xa[k] * W1r[k * HIDDEN + f];
    h1[n * HIDDEN + f] = fmaxf(acc, 0.f);
}

// Layer 2 aggregation: one wave per node, 4 floats per lane (256 features)
__global__ void agg2_kernel(const float* __restrict__ h1, const int* __restrict__ off,
                            const int* __restrict__ csr, const float* __restrict__ invdeg,
                            float* __restrict__ agg2) {
    int wave = threadIdx.x >> 6;
    int lane = threadIdx.x & 63;
    int n = blockIdx.x * 4 + wave;
    if (n >= N_NODES) return;
    float4 acc = {0.f, 0.f, 0.f, 0.f};
    int e0 = off[n], e1 = off[n + 1];
    for (int e = e0; e < e1; ++e) {
        int s = csr[e];
        float4 v = *reinterpret_cast<const float4*>(&h1[s * HIDDEN + lane * 4]);
        acc.x += v.x; acc.y += v.y; acc.z += v.z; acc.w += v.w;
    }
    float inv = invdeg[n];
    acc.x *= inv; acc.y *= inv; acc.z *= inv; acc.w *= inv;
    *reinterpret_cast<float4*>(&agg2[n * HIDDEN + lane * 4]) = acc;
}

// ---------------------------------------------------------------------------
// Layer 2 dense fused with output projection:
// h2 = relu(agg2 @ W2_l + b2 + h1 @ W2_r)  (128x128 tile, 8x8/thread fp32)
// then partial logits = h2_tile @ W_out accumulated into logits[] via atomics.
#define BM 128
#define BN 128
#define BK 16

__global__ __launch_bounds__(256) void dense2_kernel(
    const float* __restrict__ agg2, const float* __restrict__ h1,
    const float* __restrict__ W2l, const float* __restrict__ W2r,
    const float* __restrict__ b2, const float* __restrict__ Wout,
    float* __restrict__ logits) {
    __shared__ float As[BK][BM];
    __shared__ float Bs[BK][BN];
    int tid = threadIdx.x;
    int tx = tid & 15, ty = tid >> 4;
    int row0 = blockIdx.x * BM;
    int col0 = blockIdx.y * BN;

    float acc[8][8] = {};

    for (int phase = 0; phase < 2; ++phase) {
        const float* A = phase ? h1 : agg2;
        const float* B = phase ? W2r : W2l;
        for (int k0 = 0; k0 < HIDDEN; k0 += BK) {
            // A tile: 128 rows x 16 k (transposed store)
            {
                int r = tid >> 2;
                int kk = (tid & 3) * 4;
#pragma unroll
                for (int l = 0; l < 2; ++l) {
                    int row = r + l * 64;
                    int grow = row0 + row;
                    float4 v = {0.f, 0.f, 0.f, 0.f};
                    if (grow < N_NODES)
                        v = *reinterpret_cast<const float4*>(&A[(size_t)grow * HIDDEN + k0 + kk]);
                    As[kk + 0][row] = v.x;
                    As[kk + 1][row] = v.y;
                    As[kk + 2][row] = v.z;
                    As[kk + 3][row] = v.w;
                }
            }
            // B tile: 16 k x 128 cols
            {
                int kk = tid >> 4;
                int c = (tid & 15) * 8;
                float4 v0 = *reinterpret_cast<const float4*>(&B[(k0 + kk) * HIDDEN + col0 + c]);
                float4 v1 = *reinterpret_cast<const float4*>(&B[(k0 + kk) * HIDDEN + col0 + c + 4]);
                *reinterpret_cast<float4*>(&Bs[kk][c]) = v0;
                *reinterpret_cast<float4*>(&Bs[kk][c + 4]) = v1;
            }
            __syncthreads();
#pragma unroll
            for (int kk = 0; kk < BK; ++kk) {
                float a[8], b[8];
#pragma unroll
                for (int i = 0; i < 8; ++i) a[i] = As[kk][ty * 8 + i];
#pragma unroll
                for (int j = 0; j < 8; ++j) b[j] = Bs[kk][tx * 8 + j];
#pragma unroll
                for (int i = 0; i < 8; ++i)
#pragma unroll
                    for (int j = 0; j < 8; ++j) acc[i][j] += a[i] * b[j];
            }
            __syncthreads();
        }
    }

    // Epilogue: relu(acc + b2) -> partial logits -> shuffle-reduce over tx -> atomic
    float bias[8];
#pragma unroll
    for (int j = 0; j < 8; ++j) bias[j] = b2[col0 + tx * 8 + j];

#pragma unroll
    for (int i = 0; i < 8; ++i) {
        float pl[NCLASS] = {0.f, 0.f, 0.f, 0.f, 0.f};
#pragma unroll
        for (int j = 0; j < 8; ++j) {
            float h = fmaxf(acc[i][j] + bias[j], 0.f);
            int gcol = col0 + tx * 8 + j;
#pragma unroll
            for (int c = 0; c < NCLASS; ++c) pl[c] += h * Wout[gcol * NCLASS + c];
        }
#pragma unroll
        for (int c = 0; c < NCLASS; ++c) {
#pragma unroll
            for (int m = 8; m >= 1; m >>= 1) pl[c] += __shfl_xor(pl[c], m, 64);
        }
        if (tx == 0) {
            int grow = row0 + ty * 8 + i;
            if (grow < N_NODES) {
#pragma unroll
                for (int c = 0; c < NCLASS; ++c) atomicAdd(&logits[grow * NCLASS + c], pl[c]);
            }
        }
    }
}

// Softmax over 5 logits per node
__global__ void softmax_kernel(const float* __restrict__ logits, const float* __restrict__ bout,
                               float* __restrict__ out) {
    int n = blockIdx.x * 256 + threadIdx.x;
    if (n >= N_NODES) return;
    float l[NCLASS];
    float m = -1e30f;
#pragma unroll
    for (int c = 0; c < NCLASS; ++c) {
        l[c] = logits[n * NCLASS + c] + bout[c];
        m = fmaxf(m, l[c]);
    }
    float s = 0.f;
#pragma unroll
    for (int c = 0; c < NCLASS; ++c) {
        l[c] = expf(l[c] - m);
        s += l[c];
    }
    float inv = 1.f / s;
#pragma unroll
    for (int c = 0; c < NCLASS; ++c) out[n * NCLASS + c] = l[c] * inv;
}

// ---------------------------------------------------------------------------
extern "C" void kernel_launch(void* const* d_in, const int* in_sizes, int n_in,
                              void* d_out, int out_size, void* d_ws, size_t ws_size,
                              hipStream_t stream) {
    const float* x    = (const float*)d_in[0];
    const int*   eraw = (const int*)d_in[1];
    const float* W1l  = (const float*)d_in[2];
    const float* b1   = (const float*)d_in[3];
    const float* W1r  = (const float*)d_in[4];
    const float* W2l  = (const float*)d_in[5];
    const float* b2   = (const float*)d_in[6];
    const float* W2r  = (const float*)d_in[7];
    const float* Wout = (const float*)d_in[8];
    const float* bout = (const float*)d_in[9];
    float* out = (float*)d_out;

    char* p = (char*)d_ws;
    auto alloc = [&](size_t bytes) -> void* {
        void* r = (void*)p;
        p += (bytes + 255) & ~(size_t)255;
        return r;
    };
    int*   ei     = (int*)alloc((size_t)2 * N_EDGES * 4);
    int*   cnt    = (int*)alloc((size_t)N_NODES * 4);
    int*   off    = (int*)alloc((size_t)(N_NODES + 1) * 4);
    int*   cursor = (int*)alloc((size_t)N_NODES * 4);
    float* invdeg = (float*)alloc((size_t)N_NODES * 4);
    int*   csr    = (int*)alloc((size_t)N_EDGES * 4);
    float* agg1   = (float*)alloc((size_t)N_NODES * NFEAT * 4);
    float* h1     = (float*)alloc((size_t)N_NODES * HIDDEN * 4);
    float* agg2   = (float*)alloc((size_t)N_NODES * HIDDEN * 4);
    float* logits = (float*)alloc((size_t)N_NODES * NCLASS * 4);
    int*   flag   = (int*)alloc(256);

    hipMemsetAsync(cnt, 0, (size_t)N_NODES * 4, stream);
    hipMemsetAsync(logits, 0, (size_t)N_NODES * NCLASS * 4, stream);

    detect_kernel<<<1, 1024, 0, stream>>>(eraw, flag);
    normalize_kernel<<<(2 * N_EDGES + 255) / 256, 256, 0, stream>>>(eraw, flag, ei);
    count_kernel<<<(N_EDGES + 255) / 256, 256, 0, stream>>>(ei, cnt);
    scan_kernel<<<1, 1024, 0, stream>>>(cnt, off, cursor, invdeg);
    scatter_kernel<<<(N_EDGES + 255) / 256, 256, 0, stream>>>(ei, cursor, csr);

    agg1_kernel<<<(N_NODES + 255) / 256, 256, 0, stream>>>(x, off, csr, invdeg, agg1);
    dense1_kernel<<<N_NODES, HIDDEN, 0, stream>>>(x, agg1, W1l, b1, W1r, h1);
    agg2_kernel<<<(N_NODES + 3) / 4, 256, 0, stream>>>(h1, off, csr, invdeg, agg2);

    dim3 g2((N_NODES + BM - 1) / BM, HIDDEN / BN);
    dense2_kernel<<<g2, 256, 0, stream>>>(agg2, h1, W2l, W2r, b2, Wout, logits);

    softmax_kernel<<<(N_NODES + 255) / 256, 256, 0, stream>>>(logits, bout, out);
}

// Round 2
// 388.247 us; speedup vs baseline: 1.8081x; 1.8081x over previous
//
#include <hip/hip_runtime.h>
#include <hip/hip_bf16.h>

#define N_NODES 50000
#define NFEAT 5
#define HIDDEN 256
#define NCLASS 5
#define N_EDGES 800000
#define M_PAD 50048   // 391 * 128

typedef short bf16x8_t __attribute__((ext_vector_type(8)));
typedef float f32x4_t  __attribute__((ext_vector_type(4)));

static __device__ __forceinline__ float bf2f(unsigned short u) {
    unsigned int x = ((unsigned int)u) << 16;
    return __builtin_bit_cast(float, x);
}
static __device__ __forceinline__ unsigned short f2bf(float f) {
    unsigned int x = __builtin_bit_cast(unsigned int, f);
    unsigned int r = x + 0x7FFFu + ((x >> 16) & 1u);   // RNE
    return (unsigned short)(r >> 16);
}

// ---------------------------------------------------------------------------
// Edge dtype detect: int64 input => all odd 32-bit words (high halves) zero.
// flag (pre-zeroed) set to 1 iff some odd word nonzero => input is int32.
__global__ void detect_kernel(const int* __restrict__ raw, int* __restrict__ flag) {
    int v = 0;
    for (int i = blockIdx.x * 256 + threadIdx.x; i < N_EDGES; i += 256 * 256)
        v |= raw[2 * i + 1];
    unsigned long long b = __ballot(v != 0);
    if (b != 0ull && (threadIdx.x & 63) == 0) atomicOr(flag, 1);
}

__global__ void normalize_kernel(const int* __restrict__ raw, const int* __restrict__ flag,
                                 int* __restrict__ ei) {
    int i = blockIdx.x * 256 + threadIdx.x;
    if (i >= 2 * N_EDGES) return;
    int is32 = *flag;
    ei[i] = is32 ? raw[i] : raw[2 * i];
}

// ---------------------------------------------------------------------------
// CSR build
__global__ void count_kernel(const int* __restrict__ ei, int* __restrict__ cnt) {
    int e = blockIdx.x * 256 + threadIdx.x;
    if (e < N_EDGES) atomicAdd(&cnt[ei[N_EDGES + e]], 1);
}

__global__ void scan_kernel(const int* __restrict__ cnt, int* __restrict__ off,
                            int* __restrict__ cursor, float* __restrict__ invdeg) {
    __shared__ int wsum[16];
    __shared__ int carry;
    int tid = threadIdx.x;
    int lane = tid & 63, wid = tid >> 6;
    if (tid == 0) carry = 0;
    __syncthreads();
    for (int base = 0; base < N_NODES; base += 1024) {
        int i = base + tid;
        int v = (i < N_NODES) ? cnt[i] : 0;
        int s = v;
#pragma unroll
        for (int o = 1; o < 64; o <<= 1) {
            int t = __shfl_up(s, o, 64);
            if (lane >= o) s += t;
        }
        if (lane == 63) wsum[wid] = s;
        __syncthreads();
        if (wid == 0) {
            int ws = (lane < 16) ? wsum[lane] : 0;
#pragma unroll
            for (int o = 1; o < 16; o <<= 1) {
                int t = __shfl_up(ws, o, 64);
                if (lane >= o) ws += t;
            }
            if (lane < 16) wsum[lane] = ws;
        }
        __syncthreads();
        int wbase = wid ? wsum[wid - 1] : 0;
        int excl = carry + wbase + s - v;
        if (i < N_NODES) {
            off[i] = excl;
            cursor[i] = excl;
            invdeg[i] = 1.0f / fmaxf((float)v, 1.0f);
        }
        __syncthreads();
        if (tid == 0) carry += wsum[15];
        __syncthreads();
    }
    if (tid == 0) off[N_NODES] = carry;
}

__global__ void scatter_kernel(const int* __restrict__ ei, int* __restrict__ cursor,
                               int* __restrict__ csr) {
    int e = blockIdx.x * 256 + threadIdx.x;
    if (e < N_EDGES) {
        int src = ei[e], dst = ei[N_EDGES + e];
        int pos = atomicAdd(&cursor[dst], 1);
        csr[pos] = src;
    }
}

// ---------------------------------------------------------------------------
// Layer 1
__global__ void agg1_kernel(const float* __restrict__ x, const int* __restrict__ off,
                            const int* __restrict__ csr, const float* __restrict__ invdeg,
                            float* __restrict__ agg1) {
    int n = blockIdx.x * 256 + threadIdx.x;
    if (n >= N_NODES) return;
    float a[NFEAT] = {0.f, 0.f, 0.f, 0.f, 0.f};
    int e0 = off[n], e1 = off[n + 1];
    for (int e = e0; e < e1; ++e) {
        int s = csr[e];
#pragma unroll
        for (int k = 0; k < NFEAT; ++k) a[k] += x[s * NFEAT + k];
    }
    float inv = invdeg[n];
#pragma unroll
    for (int k = 0; k < NFEAT; ++k) agg1[n * NFEAT + k] = a[k] * inv;
}

// h1 (bf16) = relu(agg1 @ W1_l + b1 + x @ W1_r)
__global__ void dense1_kernel(const float* __restrict__ x, const float* __restrict__ agg1,
                              const float* __restrict__ W1l, const float* __restrict__ b1,
                              const float* __restrict__ W1r, unsigned short* __restrict__ h1b) {
    int n = blockIdx.x;
    __shared__ float xa[NFEAT], ag[NFEAT];
    int f = threadIdx.x;
    if (f < NFEAT) {
        xa[f] = x[n * NFEAT + f];
        ag[f] = agg1[n * NFEAT + f];
    }
    __syncthreads();
    float acc = b1[f];
#pragma unroll
    for (int k = 0; k < NFEAT; ++k)
        acc += ag[k] * W1l[k * HIDDEN + f] + xa[k] * W1r[k * HIDDEN + f];
    h1b[(size_t)n * HIDDEN + f] = f2bf(fmaxf(acc, 0.f));
}

// Layer 2 aggregation over bf16 h1 (one wave per node, 4 bf16 per lane)
__global__ void agg2_kernel(const unsigned short* __restrict__ h1b, const int* __restrict__ off,
                            const int* __restrict__ csr, const float* __restrict__ invdeg,
                            unsigned short* __restrict__ aggb) {
    int wave = threadIdx.x >> 6;
    int lane = threadIdx.x & 63;
    int n = blockIdx.x * 4 + wave;
    if (n >= N_NODES) return;
    float a0 = 0.f, a1 = 0.f, a2 = 0.f, a3 = 0.f;
    int e0 = off[n], e1 = off[n + 1];
    for (int e = e0; e < e1; ++e) {
        int s = csr[e];
        ushort4 v = *reinterpret_cast<const ushort4*>(&h1b[(size_t)s * HIDDEN + lane * 4]);
        a0 += bf2f(v.x); a1 += bf2f(v.y); a2 += bf2f(v.z); a3 += bf2f(v.w);
    }
    float inv = invdeg[n];
    ushort4 o;
    o.x = f2bf(a0 * inv); o.y = f2bf(a1 * inv); o.z = f2bf(a2 * inv); o.w = f2bf(a3 * inv);
    *reinterpret_cast<ushort4*>(&aggb[(size_t)n * HIDDEN + lane * 4]) = o;
}

// Pre-transpose combined weights to Wt[n][k] bf16, n in [0,256), k in [0,512)
__global__ void prep_wt(const float* __restrict__ W2l, const float* __restrict__ W2r,
                        unsigned short* __restrict__ Wt) {
    int idx = blockIdx.x * 256 + threadIdx.x;
    if (idx >= 256 * 512) return;
    int n = idx >> 9, k = idx & 511;
    float v = (k < 256) ? W2l[k * HIDDEN + n] : W2r[(k - 256) * HIDDEN + n];
    Wt[idx] = f2bf(v);
}

// ---------------------------------------------------------------------------
// Layer-2 GEMM via bf16 MFMA, fused with output projection into logits.
// A = [aggb | h1b] (M_PAD x 512 bf16), B = Wt (256 x 512 bf16, [col][k]).
// Tile 128x128, BK=64, 4 waves (2x2), per wave 64x64 (4x4 of 16x16x32).
// LDS XOR-swizzle: logical (row, chunk c of 8 bf16) stored at
// byte = row*128 + ((c ^ (row&7)) << 4); staged via global_load_lds with
// pre-swizzled per-lane global source (linear LDS dest).
__global__ __launch_bounds__(256) void dense2_mfma(
    const unsigned short* __restrict__ aggb, const unsigned short* __restrict__ h1b,
    const unsigned short* __restrict__ Wt, const float* __restrict__ b2,
    const float* __restrict__ Wout, float* __restrict__ logits) {
    __shared__ __align__(1024) char As[128 * 64 * 2];
    __shared__ __align__(1024) char Bs[128 * 64 * 2];

    int tid = threadIdx.x;
    int l = tid & 63, w = tid >> 6;
    int wm = w & 1, wn = w >> 1;
    int row0 = blockIdx.x * 128;
    int col0 = blockIdx.y * 128;

    f32x4_t acc[4][4];
#pragma unroll
    for (int m = 0; m < 4; ++m)
#pragma unroll
        for (int n = 0; n < 4; ++n)
#pragma unroll
            for (int r = 0; r < 4; ++r) acc[m][n][r] = 0.f;

    // per-lane staging source swizzle: lane l covers phys chunk (l&7) of
    // row sub-index (l>>3); logical chunk c = (l&7) ^ (l>>3)
    int srow = l >> 3;
    int sc = (l & 7) ^ srow;

    for (int k0 = 0; k0 < 2 * HIDDEN; k0 += 64) {
        const unsigned short* Asrc =
            (k0 < HIDDEN) ? (aggb + (size_t)row0 * HIDDEN + k0)
                          : (h1b + (size_t)row0 * HIDDEN + (k0 - HIDDEN));
        const unsigned short* Bsrc = Wt + (size_t)col0 * 512 + k0;
#pragma unroll
        for (int i = 0; i < 4; ++i) {
            int rr = 32 * w + 8 * i + srow;
            const unsigned short* ga = Asrc + (size_t)rr * HIDDEN + sc * 8;
            const unsigned short* gb = Bsrc + (size_t)rr * 512 + sc * 8;
            __builtin_amdgcn_global_load_lds(
                (const __attribute__((address_space(1))) void*)ga,
                (__attribute__((address_space(3))) void*)(As + w * 4096 + i * 1024), 16, 0, 0);
            __builtin_amdgcn_global_load_lds(
                (const __attribute__((address_space(1))) void*)gb,
                (__attribute__((address_space(3))) void*)(Bs + w * 4096 + i * 1024), 16, 0, 0);
        }
        __syncthreads();

#pragma unroll
        for (int kk = 0; kk < 2; ++kk) {
            bf16x8_t a[4], b[4];
#pragma unroll
            for (int m = 0; m < 4; ++m) {
                int row = wm * 64 + m * 16 + (l & 15);
                int c = kk * 4 + (l >> 4);
                int byte = row * 128 + ((c ^ (row & 7)) << 4);
                a[m] = *reinterpret_cast<const bf16x8_t*>(As + byte);
            }
#pragma unroll
            for (int n = 0; n < 4; ++n) {
                int col = wn * 64 + n * 16 + (l & 15);
                int c = kk * 4 + (l >> 4);
                int byte = col * 128 + ((c ^ (col & 7)) << 4);
                b[n] = *reinterpret_cast<const bf16x8_t*>(Bs + byte);
            }
#pragma unroll
            for (int m = 0; m < 4; ++m)
#pragma unroll
                for (int n = 0; n < 4; ++n)
                    acc[m][n] = __builtin_amdgcn_mfma_f32_16x16x32_bf16(a[m], b[n], acc[m][n], 0, 0, 0);
        }
        __syncthreads();
    }

    // Epilogue: relu(acc + b2) -> partial logits -> 16-lane shuffle reduce -> atomics
    float b2c[4];
#pragma unroll
    for (int n = 0; n < 4; ++n) b2c[n] = b2[col0 + wn * 64 + n * 16 + (l & 15)];

#pragma unroll
    for (int m = 0; m < 4; ++m) {
        int rowb = row0 + wm * 64 + m * 16 + (l >> 4) * 4;
#pragma unroll
        for (int r = 0; r < 4; ++r) {
            float pl[NCLASS] = {0.f, 0.f, 0.f, 0.f, 0.f};
#pragma unroll
            for (int n = 0; n < 4; ++n) {
                int col = col0 + wn * 64 + n * 16 + (l & 15);
                float h = fmaxf(acc[m][n][r] + b2c[n], 0.f);
#pragma unroll
                for (int c = 0; c < NCLASS; ++c) pl[c] += h * Wout[col * NCLASS + c];
            }
#pragma unroll
            for (int c = 0; c < NCLASS; ++c) {
                pl[c] += __shfl_xor(pl[c], 1, 64);
                pl[c] += __shfl_xor(pl[c], 2, 64);
                pl[c] += __shfl_xor(pl[c], 4, 64);
                pl[c] += __shfl_xor(pl[c], 8, 64);
            }
            int grow = rowb + r;
            if ((l & 15) == 0 && grow < N_NODES) {
#pragma unroll
                for (int c = 0; c < NCLASS; ++c) atomicAdd(&logits[grow * NCLASS + c], pl[c]);
            }
        }
    }
}

// Softmax over 5 logits per node
__global__ void softmax_kernel(const float* __restrict__ logits, const float* __restrict__ bout,
                               float* __restrict__ out) {
    int n = blockIdx.x * 256 + threadIdx.x;
    if (n >= N_NODES) return;
    float lg[NCLASS];
    float m = -1e30f;
#pragma unroll
    for (int c = 0; c < NCLASS; ++c) {
        lg[c] = logits[n * NCLASS + c] + bout[c];
        m = fmaxf(m, lg[c]);
    }
    float s = 0.f;
#pragma unroll
    for (int c = 0; c < NCLASS; ++c) {
        lg[c] = expf(lg[c] - m);
        s += lg[c];
    }
    float inv = 1.f / s;
#pragma unroll
    for (int c = 0; c < NCLASS; ++c) out[n * NCLASS + c] = lg[c] * inv;
}

// ---------------------------------------------------------------------------
extern "C" void kernel_launch(void* const* d_in, const int* in_sizes, int n_in,
                              void* d_out, int out_size, void* d_ws, size_t ws_size,
                              hipStream_t stream) {
    const float* x    = (const float*)d_in[0];
    const int*   eraw = (const int*)d_in[1];
    const float* W1l  = (const float*)d_in[2];
    const float* b1   = (const float*)d_in[3];
    const float* W1r  = (const float*)d_in[4];
    const float* W2l  = (const float*)d_in[5];
    const float* b2   = (const float*)d_in[6];
    const float* W2r  = (const float*)d_in[7];
    const float* Wout = (const float*)d_in[8];
    const float* bout = (const float*)d_in[9];
    float* out = (float*)d_out;

    char* p = (char*)d_ws;
    auto alloc = [&](size_t bytes) -> void* {
        void* r = (void*)p;
        p += (bytes + 255) & ~(size_t)255;
        return r;
    };
    int*            ei     = (int*)alloc((size_t)2 * N_EDGES * 4);
    int*            cnt    = (int*)alloc((size_t)N_NODES * 4);
    int*            off    = (int*)alloc((size_t)(N_NODES + 1) * 4);
    int*            cursor = (int*)alloc((size_t)N_NODES * 4);
    float*          invdeg = (float*)alloc((size_t)N_NODES * 4);
    int*            csr    = (int*)alloc((size_t)N_EDGES * 4);
    float*          agg1   = (float*)alloc((size_t)N_NODES * NFEAT * 4);
    unsigned short* h1b    = (unsigned short*)alloc((size_t)M_PAD * HIDDEN * 2);
    unsigned short* aggb   = (unsigned short*)alloc((size_t)M_PAD * HIDDEN * 2);
    unsigned short* Wt     = (unsigned short*)alloc((size_t)256 * 512 * 2);
    float*          logits = (float*)alloc((size_t)N_NODES * NCLASS * 4);
    int*            flag   = (int*)alloc(256);

    hipMemsetAsync(cnt, 0, (size_t)N_NODES * 4, stream);
    hipMemsetAsync(logits, 0, (size_t)N_NODES * NCLASS * 4, stream);
    hipMemsetAsync(flag, 0, 4, stream);
    // zero padded rows (49920+80 .. 50048) of the bf16 activation buffers
    hipMemsetAsync(h1b + (size_t)N_NODES * HIDDEN, 0, (size_t)(M_PAD - N_NODES) * HIDDEN * 2, stream);
    hipMemsetAsync(aggb + (size_t)N_NODES * HIDDEN, 0, (size_t)(M_PAD - N_NODES) * HIDDEN * 2, stream);

    detect_kernel<<<256, 256, 0, stream>>>(eraw, flag);
    normalize_kernel<<<(2 * N_EDGES + 255) / 256, 256, 0, stream>>>(eraw, flag, ei);
    count_kernel<<<(N_EDGES + 255) / 256, 256, 0, stream>>>(ei, cnt);
    scan_kernel<<<1, 1024, 0, stream>>>(cnt, off, cursor, invdeg);
    scatter_kernel<<<(N_EDGES + 255) / 256, 256, 0, stream>>>(ei, cursor, csr);

    prep_wt<<<(256 * 512 + 255) / 256, 256, 0, stream>>>(W2l, W2r, Wt);

    agg1_kernel<<<(N_NODES + 255) / 256, 256, 0, stream>>>(x, off, csr, invdeg, agg1);
    dense1_kernel<<<N_NODES, HIDDEN, 0, stream>>>(x, agg1, W1l, b1, W1r, h1b);
    agg2_kernel<<<(N_NODES + 3) / 4, 256, 0, stream>>>(h1b, off, csr, invdeg, aggb);

    dim3 g2(M_PAD / 128, HIDDEN / 128);
    dense2_mfma<<<g2, 256, 0, stream>>>(aggb, h1b, Wt, b2, Wout, logits);

    softmax_kernel<<<(N_NODES + 255) / 256, 256, 0, stream>>>(logits, bout, out);
}

// Round 3
// 284.600 us; speedup vs baseline: 2.4666x; 1.3642x over previous
//
#include <hip/hip_runtime.h>
#include <hip/hip_bf16.h>

#define N_NODES 50000
#define NFEAT 5
#define HIDDEN 256
#define NCLASS 5
#define N_EDGES 800000
#define M_PAD 50048   // 391 * 128
#define NBLK ((N_NODES + 255) / 256)   // 196 scan blocks

typedef short bf16x8_t __attribute__((ext_vector_type(8)));
typedef float f32x4_t  __attribute__((ext_vector_type(4)));
typedef unsigned short ushort8_t __attribute__((ext_vector_type(8)));

static __device__ __forceinline__ float bf2f(unsigned short u) {
    unsigned int x = ((unsigned int)u) << 16;
    return __builtin_bit_cast(float, x);
}
static __device__ __forceinline__ unsigned short f2bf(float f) {
    unsigned int x = __builtin_bit_cast(unsigned int, f);
    unsigned int r = x + 0x7FFFu + ((x >> 16) & 1u);   // RNE
    return (unsigned short)(r >> 16);
}

// ---------------------------------------------------------------------------
// Edge dtype detect: int64 input => all odd 32-bit words (high halves) zero.
__global__ void detect_kernel(const int* __restrict__ raw, int* __restrict__ flag) {
    int v = 0;
    for (int i = blockIdx.x * 256 + threadIdx.x; i < N_EDGES; i += 256 * 256)
        v |= raw[2 * i + 1];
    unsigned long long b = __ballot(v != 0);
    if (b != 0ull && (threadIdx.x & 63) == 0) atomicOr(flag, 1);
}

__global__ void normalize_kernel(const int* __restrict__ raw, const int* __restrict__ flag,
                                 int* __restrict__ ei) {
    int i = blockIdx.x * 256 + threadIdx.x;
    if (i >= 2 * N_EDGES) return;
    int is32 = *flag;
    ei[i] = is32 ? raw[i] : raw[2 * i];
}

// ---------------------------------------------------------------------------
// CSR build
__global__ void count_kernel(const int* __restrict__ ei, int* __restrict__ cnt) {
    int e = blockIdx.x * 256 + threadIdx.x;
    if (e < N_EDGES) atomicAdd(&cnt[ei[N_EDGES + e]], 1);
}

// Phase A: per-block (256 counts) sums
__global__ void block_sum_kernel(const int* __restrict__ cnt, int* __restrict__ bsum) {
    int i = blockIdx.x * 256 + threadIdx.x;
    int v = (i < N_NODES) ? cnt[i] : 0;
#pragma unroll
    for (int o = 32; o >= 1; o >>= 1) v += __shfl_down(v, o, 64);
    __shared__ int ws[4];
    if ((threadIdx.x & 63) == 0) ws[threadIdx.x >> 6] = v;
    __syncthreads();
    if (threadIdx.x == 0) bsum[blockIdx.x] = ws[0] + ws[1] + ws[2] + ws[3];
}

// Phase B: scan the 196 block sums (1 block)
__global__ void scan_bsum_kernel(const int* __restrict__ bsum, int* __restrict__ boff,
                                 int* __restrict__ off) {
    __shared__ int s[256];
    int tid = threadIdx.x;
    int v = (tid < NBLK) ? bsum[tid] : 0;
    s[tid] = v;
    __syncthreads();
    for (int o = 1; o < 256; o <<= 1) {
        int t = (tid >= o) ? s[tid - o] : 0;
        __syncthreads();
        s[tid] += t;
        __syncthreads();
    }
    if (tid < NBLK) boff[tid] = s[tid] - v;
    if (tid == 255) off[N_NODES] = s[255];
}

// Phase C: in-block exclusive scan + global offset
__global__ void scan_final_kernel(const int* __restrict__ cnt, const int* __restrict__ boff,
                                  int* __restrict__ off, int* __restrict__ cursor,
                                  float* __restrict__ invdeg) {
    int b = blockIdx.x, tid = threadIdx.x;
    int i = b * 256 + tid;
    int v = (i < N_NODES) ? cnt[i] : 0;
    int lane = tid & 63, wid = tid >> 6;
    int s = v;
#pragma unroll
    for (int o = 1; o < 64; o <<= 1) {
        int t = __shfl_up(s, o, 64);
        if (lane >= o) s += t;
    }
    __shared__ int ws[4];
    if (lane == 63) ws[wid] = s;
    __syncthreads();
    int wb = 0;
    for (int k = 0; k < wid; ++k) wb += ws[k];
    int excl = boff[b] + wb + s - v;
    if (i < N_NODES) {
        off[i] = excl;
        cursor[i] = excl;
        invdeg[i] = 1.0f / fmaxf((float)v, 1.0f);
    }
}

__global__ void scatter_kernel(const int* __restrict__ ei, int* __restrict__ cursor,
                               int* __restrict__ csr) {
    int e = blockIdx.x * 256 + threadIdx.x;
    if (e < N_EDGES) {
        int src = ei[e], dst = ei[N_EDGES + e];
        int pos = atomicAdd(&cursor[dst], 1);
        csr[pos] = src;
    }
}

// ---------------------------------------------------------------------------
// Layer 1 aggregation (x is 1 MB, L2-resident; unroll 4 for MLP)
__global__ void agg1_kernel(const float* __restrict__ x, const int* __restrict__ off,
                            const int* __restrict__ csr, const float* __restrict__ invdeg,
                            float* __restrict__ agg1) {
    int n = blockIdx.x * 256 + threadIdx.x;
    if (n >= N_NODES) return;
    float a[NFEAT] = {0.f, 0.f, 0.f, 0.f, 0.f};
    int e0 = off[n], e1 = off[n + 1];
    int e = e0;
    for (; e + 4 <= e1; e += 4) {
        int s0 = csr[e], s1 = csr[e + 1], s2 = csr[e + 2], s3 = csr[e + 3];
#pragma unroll
        for (int k = 0; k < NFEAT; ++k) {
            a[k] += x[s0 * NFEAT + k] + x[s1 * NFEAT + k] +
                    x[s2 * NFEAT + k] + x[s3 * NFEAT + k];
        }
    }
    for (; e < e1; ++e) {
        int s = csr[e];
#pragma unroll
        for (int k = 0; k < NFEAT; ++k) a[k] += x[s * NFEAT + k];
    }
    float inv = invdeg[n];
#pragma unroll
    for (int k = 0; k < NFEAT; ++k) agg1[n * NFEAT + k] = a[k] * inv;
}

// h1 (bf16) = relu(agg1 @ W1_l + b1 + x @ W1_r); 32 nodes per block,
// weights held in registers (10 floats per thread)
#define D1_NODES 32
__global__ __launch_bounds__(256) void dense1_kernel(
    const float* __restrict__ x, const float* __restrict__ agg1,
    const float* __restrict__ W1l, const float* __restrict__ b1,
    const float* __restrict__ W1r, unsigned short* __restrict__ h1b) {
    int f = threadIdx.x;
    float wl[NFEAT], wr[NFEAT];
#pragma unroll
    for (int k = 0; k < NFEAT; ++k) {
        wl[k] = W1l[k * HIDDEN + f];
        wr[k] = W1r[k * HIDDEN + f];
    }
    float bb = b1[f];
    int n0 = blockIdx.x * D1_NODES;
    __shared__ float xs[D1_NODES][NFEAT], as[D1_NODES][NFEAT];
    for (int idx = f; idx < D1_NODES * NFEAT; idx += 256) {
        int nn = idx / NFEAT, kk = idx % NFEAT;
        int n = n0 + nn;
        if (n < N_NODES) {
            xs[nn][kk] = x[n * NFEAT + kk];
            as[nn][kk] = agg1[n * NFEAT + kk];
        }
    }
    __syncthreads();
#pragma unroll 4
    for (int j = 0; j < D1_NODES; ++j) {
        int n = n0 + j;
        if (n >= N_NODES) break;
        float acc = bb;
#pragma unroll
        for (int k = 0; k < NFEAT; ++k) acc += as[j][k] * wl[k] + xs[j][k] * wr[k];
        h1b[(size_t)n * HIDDEN + f] = f2bf(fmaxf(acc, 0.f));
    }
}

// ---------------------------------------------------------------------------
// Layer 2 aggregation: 32 lanes x 16B per row (2 nodes per wave), 4-edge unroll
__global__ __launch_bounds__(256) void agg2_kernel(
    const unsigned short* __restrict__ h1b, const int* __restrict__ off,
    const int* __restrict__ csr, const float* __restrict__ invdeg,
    unsigned short* __restrict__ aggb) {
    int tid = threadIdx.x;
    int n = blockIdx.x * 8 + ((tid >> 6) << 1) + ((tid >> 5) & 1);
    if (n >= N_NODES) return;
    int lane32 = tid & 31;
    size_t fb = (size_t)lane32 * 8;

    float a[8] = {0.f, 0.f, 0.f, 0.f, 0.f, 0.f, 0.f, 0.f};
    int e0 = off[n], e1 = off[n + 1];
    int e = e0;
    for (; e + 4 <= e1; e += 4) {
        int s0 = csr[e], s1 = csr[e + 1], s2 = csr[e + 2], s3 = csr[e + 3];
        ushort8_t v0 = *reinterpret_cast<const ushort8_t*>(&h1b[(size_t)s0 * HIDDEN + fb]);
        ushort8_t v1 = *reinterpret_cast<const ushort8_t*>(&h1b[(size_t)s1 * HIDDEN + fb]);
        ushort8_t v2 = *reinterpret_cast<const ushort8_t*>(&h1b[(size_t)s2 * HIDDEN + fb]);
        ushort8_t v3 = *reinterpret_cast<const ushort8_t*>(&h1b[(size_t)s3 * HIDDEN + fb]);
#pragma unroll
        for (int k = 0; k < 8; ++k)
            a[k] += (bf2f(v0[k]) + bf2f(v1[k])) + (bf2f(v2[k]) + bf2f(v3[k]));
    }
    for (; e < e1; ++e) {
        int s = csr[e];
        ushort8_t v = *reinterpret_cast<const ushort8_t*>(&h1b[(size_t)s * HIDDEN + fb]);
#pragma unroll
        for (int k = 0; k < 8; ++k) a[k] += bf2f(v[k]);
    }
    float inv = invdeg[n];
    ushort8_t o;
#pragma unroll
    for (int k = 0; k < 8; ++k) o[k] = f2bf(a[k] * inv);
    *reinterpret_cast<ushort8_t*>(&aggb[(size_t)n * HIDDEN + fb]) = o;
}

// Pre-transpose combined weights to Wt[n][k] bf16, n in [0,256), k in [0,512)
__global__ void prep_wt(const float* __restrict__ W2l, const float* __restrict__ W2r,
                        unsigned short* __restrict__ Wt) {
    int idx = blockIdx.x * 256 + threadIdx.x;
    if (idx >= 256 * 512) return;
    int n = idx >> 9, k = idx & 511;
    float v = (k < 256) ? W2l[k * HIDDEN + n] : W2r[(k - 256) * HIDDEN + n];
    Wt[idx] = f2bf(v);
}

// ---------------------------------------------------------------------------
// Layer-2 GEMM via bf16 MFMA, fused with output projection into logits.
__global__ __launch_bounds__(256) void dense2_mfma(
    const unsigned short* __restrict__ aggb, const unsigned short* __restrict__ h1b,
    const unsigned short* __restrict__ Wt, const float* __restrict__ b2,
    const float* __restrict__ Wout, float* __restrict__ logits) {
    __shared__ __align__(1024) char As[128 * 64 * 2];
    __shared__ __align__(1024) char Bs[128 * 64 * 2];

    int tid = threadIdx.x;
    int l = tid & 63, w = tid >> 6;
    int wm = w & 1, wn = w >> 1;
    int row0 = blockIdx.x * 128;
    int col0 = blockIdx.y * 128;

    f32x4_t acc[4][4];
#pragma unroll
    for (int m = 0; m < 4; ++m)
#pragma unroll
        for (int n = 0; n < 4; ++n)
#pragma unroll
            for (int r = 0; r < 4; ++r) acc[m][n][r] = 0.f;

    int srow = l >> 3;
    int sc = (l & 7) ^ srow;

    for (int k0 = 0; k0 < 2 * HIDDEN; k0 += 64) {
        const unsigned short* Asrc =
            (k0 < HIDDEN) ? (aggb + (size_t)row0 * HIDDEN + k0)
                          : (h1b + (size_t)row0 * HIDDEN + (k0 - HIDDEN));
        const unsigned short* Bsrc = Wt + (size_t)col0 * 512 + k0;
#pragma unroll
        for (int i = 0; i < 4; ++i) {
            int rr = 32 * w + 8 * i + srow;
            const unsigned short* ga = Asrc + (size_t)rr * HIDDEN + sc * 8;
            const unsigned short* gb = Bsrc + (size_t)rr * 512 + sc * 8;
            __builtin_amdgcn_global_load_lds(
                (const __attribute__((address_space(1))) void*)ga,
                (__attribute__((address_space(3))) void*)(As + w * 4096 + i * 1024), 16, 0, 0);
            __builtin_amdgcn_global_load_lds(
                (const __attribute__((address_space(1))) void*)gb,
                (__attribute__((address_space(3))) void*)(Bs + w * 4096 + i * 1024), 16, 0, 0);
        }
        __syncthreads();

#pragma unroll
        for (int kk = 0; kk < 2; ++kk) {
            bf16x8_t a[4], b[4];
#pragma unroll
            for (int m = 0; m < 4; ++m) {
                int row = wm * 64 + m * 16 + (l & 15);
                int c = kk * 4 + (l >> 4);
                int byte = row * 128 + ((c ^ (row & 7)) << 4);
                a[m] = *reinterpret_cast<const bf16x8_t*>(As + byte);
            }
#pragma unroll
            for (int n = 0; n < 4; ++n) {
                int col = wn * 64 + n * 16 + (l & 15);
                int c = kk * 4 + (l >> 4);
                int byte = col * 128 + ((c ^ (col & 7)) << 4);
                b[n] = *reinterpret_cast<const bf16x8_t*>(Bs + byte);
            }
#pragma unroll
            for (int m = 0; m < 4; ++m)
#pragma unroll
                for (int n = 0; n < 4; ++n)
                    acc[m][n] = __builtin_amdgcn_mfma_f32_16x16x32_bf16(a[m], b[n], acc[m][n], 0, 0, 0);
        }
        __syncthreads();
    }

    float b2c[4];
#pragma unroll
    for (int n = 0; n < 4; ++n) b2c[n] = b2[col0 + wn * 64 + n * 16 + (l & 15)];

#pragma unroll
    for (int m = 0; m < 4; ++m) {
        int rowb = row0 + wm * 64 + m * 16 + (l >> 4) * 4;
#pragma unroll
        for (int r = 0; r < 4; ++r) {
            float pl[NCLASS] = {0.f, 0.f, 0.f, 0.f, 0.f};
#pragma unroll
            for (int n = 0; n < 4; ++n) {
                int col = col0 + wn * 64 + n * 16 + (l & 15);
                float h = fmaxf(acc[m][n][r] + b2c[n], 0.f);
#pragma unroll
                for (int c = 0; c < NCLASS; ++c) pl[c] += h * Wout[col * NCLASS + c];
            }
#pragma unroll
            for (int c = 0; c < NCLASS; ++c) {
                pl[c] += __shfl_xor(pl[c], 1, 64);
                pl[c] += __shfl_xor(pl[c], 2, 64);
                pl[c] += __shfl_xor(pl[c], 4, 64);
                pl[c] += __shfl_xor(pl[c], 8, 64);
            }
            int grow = rowb + r;
            if ((l & 15) == 0 && grow < N_NODES) {
#pragma unroll
                for (int c = 0; c < NCLASS; ++c) atomicAdd(&logits[grow * NCLASS + c], pl[c]);
            }
        }
    }
}

// Softmax over 5 logits per node
__global__ void softmax_kernel(const float* __restrict__ logits, const float* __restrict__ bout,
                               float* __restrict__ out) {
    int n = blockIdx.x * 256 + threadIdx.x;
    if (n >= N_NODES) return;
    float lg[NCLASS];
    float m = -1e30f;
#pragma unroll
    for (int c = 0; c < NCLASS; ++c) {
        lg[c] = logits[n * NCLASS + c] + bout[c];
        m = fmaxf(m, lg[c]);
    }
    float s = 0.f;
#pragma unroll
    for (int c = 0; c < NCLASS; ++c) {
        lg[c] = expf(lg[c] - m);
        s += lg[c];
    }
    float inv = 1.f / s;
#pragma unroll
    for (int c = 0; c < NCLASS; ++c) out[n * NCLASS + c] = lg[c] * inv;
}

// ---------------------------------------------------------------------------
extern "C" void kernel_launch(void* const* d_in, const int* in_sizes, int n_in,
                              void* d_out, int out_size, void* d_ws, size_t ws_size,
                              hipStream_t stream) {
    const float* x    = (const float*)d_in[0];
    const int*   eraw = (const int*)d_in[1];
    const float* W1l  = (const float*)d_in[2];
    const float* b1   = (const float*)d_in[3];
    const float* W1r  = (const float*)d_in[4];
    const float* W2l  = (const float*)d_in[5];
    const float* b2   = (const float*)d_in[6];
    const float* W2r  = (const float*)d_in[7];
    const float* Wout = (const float*)d_in[8];
    const float* bout = (const float*)d_in[9];
    float* out = (float*)d_out;

    char* p = (char*)d_ws;
    auto alloc = [&](size_t bytes) -> void* {
        void* r = (void*)p;
        p += (bytes + 255) & ~(size_t)255;
        return r;
    };
    int*            ei     = (int*)alloc((size_t)2 * N_EDGES * 4);
    int*            cnt    = (int*)alloc((size_t)N_NODES * 4);
    int*            off    = (int*)alloc((size_t)(N_NODES + 1) * 4);
    int*            cursor = (int*)alloc((size_t)N_NODES * 4);
    float*          invdeg = (float*)alloc((size_t)N_NODES * 4);
    int*            csr    = (int*)alloc((size_t)N_EDGES * 4);
    float*          agg1   = (float*)alloc((size_t)N_NODES * NFEAT * 4);
    unsigned short* h1b    = (unsigned short*)alloc((size_t)M_PAD * HIDDEN * 2);
    unsigned short* aggb   = (unsigned short*)alloc((size_t)M_PAD * HIDDEN * 2);
    unsigned short* Wt     = (unsigned short*)alloc((size_t)256 * 512 * 2);
    float*          logits = (float*)alloc((size_t)N_NODES * NCLASS * 4);
    int*            bsum   = (int*)alloc((size_t)NBLK * 4);
    int*            boff   = (int*)alloc((size_t)NBLK * 4);
    int*            flag   = (int*)alloc(256);

    hipMemsetAsync(cnt, 0, (size_t)N_NODES * 4, stream);
    hipMemsetAsync(logits, 0, (size_t)N_NODES * NCLASS * 4, stream);
    hipMemsetAsync(flag, 0, 4, stream);
    hipMemsetAsync(h1b + (size_t)N_NODES * HIDDEN, 0, (size_t)(M_PAD - N_NODES) * HIDDEN * 2, stream);
    hipMemsetAsync(aggb + (size_t)N_NODES * HIDDEN, 0, (size_t)(M_PAD - N_NODES) * HIDDEN * 2, stream);

    detect_kernel<<<256, 256, 0, stream>>>(eraw, flag);
    normalize_kernel<<<(2 * N_EDGES + 255) / 256, 256, 0, stream>>>(eraw, flag, ei);
    count_kernel<<<(N_EDGES + 255) / 256, 256, 0, stream>>>(ei, cnt);
    block_sum_kernel<<<NBLK, 256, 0, stream>>>(cnt, bsum);
    scan_bsum_kernel<<<1, 256, 0, stream>>>(bsum, boff, off);
    scan_final_kernel<<<NBLK, 256, 0, stream>>>(cnt, boff, off, cursor, invdeg);
    scatter_kernel<<<(N_EDGES + 255) / 256, 256, 0, stream>>>(ei, cursor, csr);

    prep_wt<<<(256 * 512 + 255) / 256, 256, 0, stream>>>(W2l, W2r, Wt);

    agg1_kernel<<<(N_NODES + 255) / 256, 256, 0, stream>>>(x, off, csr, invdeg, agg1);
    dense1_kernel<<<(N_NODES + D1_NODES - 1) / D1_NODES, 256, 0, stream>>>(x, agg1, W1l, b1, W1r, h1b);
    agg2_kernel<<<(N_NODES + 7) / 8, 256, 0, stream>>>(h1b, off, csr, invdeg, aggb);

    dim3 g2(M_PAD / 128, HIDDEN / 128);
    dense2_mfma<<<g2, 256, 0, stream>>>(aggb, h1b, Wt, b2, Wout, logits);

    softmax_kernel<<<(N_NODES + 255) / 256, 256, 0, stream>>>(logits, bout, out);
}